// Round 9
// baseline (300.195 us; speedup 1.0000x reference)
//
#include <hip/hip_runtime.h>
#include <hip/hip_bf16.h>

#define NK 1024        // codebook size
#define ND 64          // embedding dim
#define NV 131072      // 32*64*64 input vectors
#define BR 128         // rows per assign block
#define DECAY_F 0.99f
#define OMD_F 0.01f
#define EPS_F 1e-5f
#define KEPS_F 0.01024f // fl32(1024 * 1e-5)

typedef const __attribute__((address_space(1))) void* gas1_t;
typedef __attribute__((address_space(3))) void* las3_t;
#define GLOAD_LDS16(gp, lp) \
    __builtin_amdgcn_global_load_lds((gas1_t)(gp), (las3_t)(lp), 16, 0, 0)
#define MEMFENCE asm volatile("" ::: "memory")

// ---- ws layout (bytes) ----
// 0       : csq[1024]    f32
// 4096    : cnt[1024]    i32
// 16384   : ucf[1024]    f32
// 20480   : loss         f64
// 1597440 : acc[65536]   f32 (256 KB)

// ---------------------------------------------------------------------------
// Kernel 1: codebook_sq (numpy pairwise-8 rounding); zero cnt/loss/acc.
// ---------------------------------------------------------------------------
__global__ __launch_bounds__(256) void vq_prep(const float* __restrict__ emb,
                                               float* __restrict__ csq,
                                               int* __restrict__ cnt,
                                               double* loss,
                                               float4* __restrict__ acc4)
{
    int k = blockIdx.x * 256 + threadIdx.x;
    cnt[k] = 0;
    if (k == 0) *loss = 0.0;
    float4 z = make_float4(0.f, 0.f, 0.f, 0.f);
#pragma unroll
    for (int i = 0; i < 16; ++i) acc4[k + i * 1024] = z;   // zero acc[65536]
    float p[ND];
    const float4* e4 = reinterpret_cast<const float4*>(emb + (size_t)k * ND);
#pragma unroll
    for (int i = 0; i < 16; ++i) {
        float4 v = e4[i];
        p[4*i+0] = __fmul_rn(v.x, v.x);
        p[4*i+1] = __fmul_rn(v.y, v.y);
        p[4*i+2] = __fmul_rn(v.z, v.z);
        p[4*i+3] = __fmul_rn(v.w, v.w);
    }
    float r[8];
#pragma unroll
    for (int j = 0; j < 8; ++j) r[j] = p[j];
#pragma unroll
    for (int i = 8; i < ND; i += 8)
#pragma unroll
        for (int j = 0; j < 8; ++j) r[j] = __fadd_rn(r[j], p[i+j]);
    csq[k] = __fadd_rn(__fadd_rn(__fadd_rn(r[0], r[1]), __fadd_rn(r[2], r[3])),
                       __fadd_rn(__fadd_rn(r[4], r[5]), __fadd_rn(r[6], r[7])));
}

// ---------------------------------------------------------------------------
// Kernel 2: register-tiled fp32 GEMM + fused argmin. Distance arithmetic
// byte-identical to round 8. Change: enc zero-fill spread across the 8 tile
// phases with raw s_barrier + counted s_waitcnt vmcnt(16) (T3/T4 pattern) —
// stores stay in flight across barriers and drain under the next tile's
// compute, so the 537 MB enc stream overlaps the GEMM instead of bursting
// in the epilogue.
// ---------------------------------------------------------------------------
__global__ __launch_bounds__(256, 2) void vq_assign(
    const float* __restrict__ x_in, const float* __restrict__ emb,
    const float* __restrict__ csq, float* __restrict__ out_qf,
    float* __restrict__ out_enc, float* __restrict__ acc_buf,
    int* __restrict__ cnt, double* __restrict__ loss_acc)
{
    __shared__ __align__(16) float xs[BR * ND];    // 32 KB, swizzled
    __shared__ __align__(16) float es[128 * ND];   // 32 KB, swizzled
    __shared__ float csq_s[NK];
    __shared__ float isq_s[BR];
    __shared__ double lds_ls[4];

    const int tid  = threadIdx.x;
    const int lane = tid & 63;
    const int wv   = tid >> 6;
    const int tx   = tid & 15;
    const int ty   = tid >> 4;
    const int txs  = tx & 7;
    const int tys  = ty & 7;
    const size_t rowbase = (size_t)blockIdx.x * BR;
    const float4 zv = make_float4(0.f, 0.f, 0.f, 0.f);

    // ---- stage xs + es(tile 0) via async DMA; csq via regular copy ----
#pragma unroll
    for (int c = 0; c < 8; ++c) {
        int f = tid + c * 256;
        int row = f >> 4, ch = f & 15;
        int sch = ch ^ (row & 7);
        GLOAD_LDS16(x_in + rowbase * ND + row * ND + sch * 4, &xs[f * 4]);
    }
#pragma unroll
    for (int c = 0; c < 8; ++c) {
        int f = tid + c * 256;
        int row = f >> 4, ch = f & 15;
        int sch = ch ^ (row & 7);
        GLOAD_LDS16(emb + (size_t)row * ND + sch * 4, &es[f * 4]);
    }
#pragma unroll
    for (int c = 0; c < 4; ++c) csq_s[tid + c * 256] = csq[tid + c * 256];
    __syncthreads();   // prologue: full drain fine (no stores outstanding)

    // ---- isq per row (numpy pairwise-8 order, swizzled reads) ----
    if (tid < BR) {
        const int rs = tid & 7;
        const float* xr = &xs[tid * ND];
        float r[8];
        {
            float4 a = *(const float4*)&xr[(0 ^ rs) * 4];
            float4 b = *(const float4*)&xr[(1 ^ rs) * 4];
            r[0] = __fmul_rn(a.x, a.x); r[1] = __fmul_rn(a.y, a.y);
            r[2] = __fmul_rn(a.z, a.z); r[3] = __fmul_rn(a.w, a.w);
            r[4] = __fmul_rn(b.x, b.x); r[5] = __fmul_rn(b.y, b.y);
            r[6] = __fmul_rn(b.z, b.z); r[7] = __fmul_rn(b.w, b.w);
        }
#pragma unroll
        for (int g = 1; g < 8; ++g) {
            float4 a = *(const float4*)&xr[((2*g)   ^ rs) * 4];
            float4 b = *(const float4*)&xr[((2*g+1) ^ rs) * 4];
            r[0] = __fadd_rn(r[0], __fmul_rn(a.x, a.x));
            r[1] = __fadd_rn(r[1], __fmul_rn(a.y, a.y));
            r[2] = __fadd_rn(r[2], __fmul_rn(a.z, a.z));
            r[3] = __fadd_rn(r[3], __fmul_rn(a.w, a.w));
            r[4] = __fadd_rn(r[4], __fmul_rn(b.x, b.x));
            r[5] = __fadd_rn(r[5], __fmul_rn(b.y, b.y));
            r[6] = __fadd_rn(r[6], __fmul_rn(b.z, b.z));
            r[7] = __fadd_rn(r[7], __fmul_rn(b.w, b.w));
        }
        isq_s[tid] = __fadd_rn(__fadd_rn(__fadd_rn(r[0], r[1]), __fadd_rn(r[2], r[3])),
                               __fadd_rn(__fadd_rn(r[4], r[5]), __fadd_rn(r[6], r[7])));
    }

    float best[8];
    int   bestk[8];
#pragma unroll
    for (int i = 0; i < 8; ++i) { best[i] = 3.4e38f; bestk[i] = 0; }

    for (int t = 0; t < 8; ++t) {
        float acc[8][8];
#pragma unroll
        for (int i = 0; i < 8; ++i)
#pragma unroll
            for (int j = 0; j < 8; ++j) acc[i][j] = 0.f;

        for (int ch = 0; ch < 16; ++ch) {
            const int xo = (ch ^ tys) * 4;
            const int eo = (ch ^ txs) * 4;
            float4 xf[8], ef[8];
#pragma unroll
            for (int i = 0; i < 8; ++i)
                xf[i] = *(const float4*)&xs[(ty + 16*i) * ND + xo];
#pragma unroll
            for (int j = 0; j < 8; ++j)
                ef[j] = *(const float4*)&es[(tx + 16*j) * ND + eo];
#pragma unroll
            for (int i = 0; i < 8; ++i) {
#pragma unroll
                for (int j = 0; j < 8; ++j) {
                    float a = acc[i][j];
                    a = __builtin_fmaf(xf[i].x, ef[j].x, a);
                    a = __builtin_fmaf(xf[i].y, ef[j].y, a);
                    a = __builtin_fmaf(xf[i].z, ef[j].z, a);
                    a = __builtin_fmaf(xf[i].w, ef[j].w, a);
                    acc[i][j] = a;
                }
            }
        }

        // compare (codes ascend with j and t -> strict < keeps first index)
#pragma unroll
        for (int i = 0; i < 8; ++i) {
            float isq = isq_s[ty + 16*i];
#pragma unroll
            for (int j = 0; j < 8; ++j) {
                float dist = __fsub_rn(__fadd_rn(isq, csq_s[t * 128 + tx + 16*j]),
                                       __fmul_rn(2.0f, acc[i][j]));
                if (dist < best[i]) { best[i] = dist; bestk[i] = t * 128 + tx + 16*j; }
            }
        }

        // ---- phase boundary: raw barrier (NO vmcnt drain) ----
        MEMFENCE;
        __builtin_amdgcn_s_barrier();   // all waves done reading es tile t
        MEMFENCE;

        if (t < 7) {                    // issue next es tile DMA first...
#pragma unroll
            for (int c = 0; c < 8; ++c) {
                int f = tid + c * 256;
                int row = f >> 4, ch = f & 15;
                int sch = ch ^ (row & 7);
                GLOAD_LDS16(emb + (size_t)(t + 1) * 128 * ND + row * ND + sch * 4,
                            &es[f * 4]);
            }
        }
        MEMFENCE;                       // pin issue order: DMA before stores
        {                               // ...then 16 enc zero stores (rows t*16..+15)
            float4* encb = reinterpret_cast<float4*>(out_enc + (rowbase + t * 16) * NK);
#pragma unroll
            for (int i = 0; i < 16; ++i)
                encb[tid + i * 256] = zv;
        }
        if (t < 7) {
            // in-order completion: <=16 outstanding => 8 DMAs (older) complete,
            // this tile's 16 stores stay in flight across the barrier.
            asm volatile("s_waitcnt vmcnt(16)" ::: "memory");
        }
        MEMFENCE;
        __builtin_amdgcn_s_barrier();   // es tile t+1 visible to all waves
        MEMFENCE;
    }

    // ---- cross-thread argmin reduction (overlay scratch on es) ----
    float* red_d = es;
    int*   red_i = reinterpret_cast<int*>(es + 2048);
#pragma unroll
    for (int i = 0; i < 8; ++i) {
        red_d[(ty + 16*i) * 16 + tx] = best[i];
        red_i[(ty + 16*i) * 16 + tx] = bestk[i];
    }
    asm volatile("s_waitcnt lgkmcnt(0)" ::: "memory");   // LDS-only sync:
    __builtin_amdgcn_s_barrier();                        // no store drain
    MEMFENCE;
    if (tid < BR) {
        float bd = red_d[tid * 16];
        int   bk = red_i[tid * 16];
#pragma unroll
        for (int c = 1; c < 16; ++c) {
            float d  = red_d[tid * 16 + c];
            int   k2 = red_i[tid * 16 + c];
            if (d < bd || (d == bd && k2 < bk)) { bd = d; bk = k2; }
        }
        atomicAdd(&cnt[bk], 1);
        red_i[tid * 16] = bk;             // publish for epilogue
    }
    asm volatile("s_waitcnt lgkmcnt(0)" ::: "memory");
    __builtin_amdgcn_s_barrier();
    MEMFENCE;

    // ---- epilogue: quantized_flow + loss + acc atomics (enc zeros already
    //      issued in tile loop; they drain under this compute) ----
    float lsum = 0.f;
    const int lsw = (lane >> 2);        // chunk of element `lane`
    for (int r = 0; r < 32; ++r) {
        int rl = wv * 32 + r;
        int kr = red_i[rl * 16];
        size_t grow = rowbase + rl;
        float xv = xs[rl * ND + ((lsw ^ (rl & 7)) << 2) + (lane & 3)];
        float ev = emb[(size_t)kr * ND + lane];
        out_qf[grow * ND + lane] = __fadd_rn(xv, __fsub_rn(ev, xv));
        float dd = __fsub_rn(xv, ev);
        lsum = __builtin_fmaf(dd, dd, lsum);
        atomicAdd(&acc_buf[(size_t)kr * ND + lane], xv);   // segment sum
    }
    double ls = (double)lsum;
#pragma unroll
    for (int off = 32; off >= 1; off >>= 1) ls += __shfl_xor(ls, off, 64);
    if (lane == 0) lds_ls[wv] = ls;

    // final drain: ALL waves' zero-stores complete before the 1.0 scatter
    asm volatile("s_waitcnt vmcnt(0)" ::: "memory");
    __syncthreads();

    if (tid < BR) {
        int bk = red_i[tid * 16];
        out_enc[(rowbase + tid) * NK + bk] = 1.0f;
    }
    if (tid == 0)
        atomicAdd(loss_acc, (lds_ls[0] + lds_ls[1]) + (lds_ls[2] + lds_ls[3]));
}

// ---------------------------------------------------------------------------
// Kernel 3: scan — uc (EMA counts), exact numpy-pairwise n via one wave's
// shuffle tree, usage/loss scalars, ucf.
// ---------------------------------------------------------------------------
__global__ __launch_bounds__(256) void vq_scan(
    const int* __restrict__ cnt, const float* __restrict__ ema_cs,
    const double* __restrict__ loss_acc, float* __restrict__ ucf_ws,
    float* __restrict__ out_uc, float* __restrict__ out_usage,
    float* __restrict__ out_loss)
{
    __shared__ float uc_s[1024];
    __shared__ int   usage_s;
    __shared__ float n_s;
    const int tid  = threadIdx.x;
    if (tid == 0) usage_s = 0;
    __syncthreads();

    int ucount = 0;
#pragma unroll
    for (int j = 0; j < 4; ++j) {
        int k = tid * 4 + j;
        int c = cnt[k];
        if (c > 0) ucount++;
        uc_s[k] = __fadd_rn(__fmul_rn(ema_cs[k], DECAY_F), __fmul_rn(OMD_F, (float)c));
    }
    atomicAdd(&usage_s, ucount);
    __syncthreads();

    // exact numpy pairwise sum of uc_s[1024]: 8 blocks x 8 accumulators,
    // combined by a commutative-safe xor tree (j bits then b bits).
    if (tid < 64) {
        int b = tid >> 3, j = tid & 7;
        float r = uc_s[b * 128 + j];
#pragma unroll
        for (int i = 1; i < 16; ++i)
            r = __fadd_rn(r, uc_s[b * 128 + 8 * i + j]);
        r = __fadd_rn(r, __shfl_xor(r, 1, 64));
        r = __fadd_rn(r, __shfl_xor(r, 2, 64));
        r = __fadd_rn(r, __shfl_xor(r, 4, 64));
        r = __fadd_rn(r, __shfl_xor(r, 8, 64));
        r = __fadd_rn(r, __shfl_xor(r, 16, 64));
        r = __fadd_rn(r, __shfl_xor(r, 32, 64));
        if (tid == 0) {
            n_s = r;
            *out_usage = __fdiv_rn((float)usage_s, 1024.0f);
            *out_loss  = (float)(*loss_acc / 8388608.0);
        }
    }
    __syncthreads();

    const float n = n_s;
#pragma unroll
    for (int j = 0; j < 4; ++j) {
        int k = tid * 4 + j;
        float ucfv = __fmul_rn(__fdiv_rn(__fadd_rn(uc_s[k], EPS_F), __fadd_rn(n, KEPS_F)), n);
        out_uc[k] = ucfv;
        ucf_ws[k] = ucfv;
    }
}

// ---------------------------------------------------------------------------
// Kernel 4: final — upd_ema_w + upd_embeddings from acc.
// ---------------------------------------------------------------------------
__global__ __launch_bounds__(256) void vq_final(
    const float* __restrict__ acc_buf, const float* __restrict__ ema_w,
    const float* __restrict__ ucf, float* __restrict__ out_updw,
    float* __restrict__ out_upde)
{
    int gid = blockIdx.x * 256 + threadIdx.x;
    int k = gid >> 6;
    float w = __fadd_rn(__fmul_rn(ema_w[gid], DECAY_F), __fmul_rn(OMD_F, acc_buf[gid]));
    out_updw[gid] = w;
    out_upde[gid] = __fdiv_rn(w, __fadd_rn(ucf[k], EPS_F));
}

// ---------------------------------------------------------------------------
extern "C" void kernel_launch(void* const* d_in, const int* in_sizes, int n_in,
                              void* d_out, int out_size, void* d_ws, size_t ws_size,
                              hipStream_t stream)
{
    const float* x_in   = (const float*)d_in[0];
    const float* emb    = (const float*)d_in[1];
    const float* ema_cs = (const float*)d_in[2];
    const float* ema_w  = (const float*)d_in[3];

    float* out_qf    = (float*)d_out;                    // [NV*64]
    float* out_enc   = out_qf + (size_t)NV * ND;         // [NV*1024]
    float* out_usage = out_enc + (size_t)NV * NK;        // [1]
    float* out_loss  = out_usage + 1;                    // [1]
    float* out_upde  = out_loss + 1;                     // [1024*64]
    float* out_uc    = out_upde + (size_t)NK * ND;       // [1024]
    float* out_updw  = out_uc + NK;                      // [1024*64]

    char* ws = (char*)d_ws;
    float*  ws_csq    = (float*)(ws);
    int*    ws_cnt    = (int*)(ws + 4096);
    float*  ws_ucf    = (float*)(ws + 16384);
    double* ws_loss   = (double*)(ws + 20480);
    float*  ws_acc    = (float*)(ws + 1597440);

    vq_prep<<<4, 256, 0, stream>>>(emb, ws_csq, ws_cnt, ws_loss, (float4*)ws_acc);
    vq_assign<<<NV / BR, 256, 0, stream>>>(x_in, emb, ws_csq, out_qf, out_enc,
                                           ws_acc, ws_cnt, ws_loss);
    vq_scan<<<1, 256, 0, stream>>>(ws_cnt, ema_cs, ws_loss, ws_ucf,
                                   out_uc, out_usage, out_loss);
    vq_final<<<256, 256, 0, stream>>>(ws_acc, ema_w, ws_ucf, out_updw, out_upde);
}